// Round 12
// baseline (132.191 us; speedup 1.0000x reference)
//
#include <hip/hip_runtime.h>
#include <math.h>

// ============================================================================
// re3: MLP-encode (3 layers + LayerNorm) of src/tgt, then fused
//      all-pairs-L2-distance + top-3-smallest + sum/2 ("state entropy").
//
// Round-12: dist12 = fp8 distance GEMM with DEEP PREFETCH VIA PRIVATE LDS.
//   - Per wave: 4 rotating 4 KB frag slots in LDS (64 KB/block), filled by
//     global_load_lds, drained by counted s_waitcnt vmcnt(12) (3 frags in
//     flight, never 0). ~1200 cyc latency coverage vs ~400 for reg prefetch.
//   - t2 staged once to 8 KB shared LDS (single barrier at start); main loop
//     has NO barriers and the only loop VMEM is the counted gloads.
//   - grid 512 = 64 row-tiles x 8 splits; 4 waves x 64 rows; 2 blocks/CU
//     (LDS 72 KB). Registers freed from B-prefetch (unified VGPR/AGPR file
//     caps waves at 2/SIMD — r10/r11 showed TLP can't rise; hide latency
//     instead).
// encode / prep / repack / merge / bf16-fallback unchanged.
// ============================================================================

typedef __attribute__((ext_vector_type(8))) short short8;
typedef __attribute__((ext_vector_type(4))) float floatx4;
typedef __attribute__((ext_vector_type(8))) int int8v;
typedef __attribute__((ext_vector_type(4))) int int4v;

#define MFMA16(a, b, c) __builtin_amdgcn_mfma_f32_16x16x32_bf16((a), (b), (c), 0, 0, 0)

__device__ __forceinline__ floatx4 mfma8(int8v a, int8v b, floatx4 c) {
  // fmt 0 = OCP e4m3 both operands; scale byte 127 = 2^0.
  return __builtin_amdgcn_mfma_scale_f32_16x16x128_f8f6f4(a, b, c, 0, 0, 0, 0x7F, 0, 0x7F);
}

__device__ __forceinline__ int8v cat8(int4v lo, int4v hi) {
  return __builtin_shufflevector(lo, hi, 0, 1, 2, 3, 4, 5, 6, 7);
}

// ---- ws layout (bytes) ----
static const size_t OFF_W1F  = 0;                       //  64 KB
static const size_t OFF_W2F  = 65536;                   // 128 KB
static const size_t OFF_W3F  = 196608;                  // 128 KB
static const size_t OFF_SRCF = 327680;                  //   8 MB bf16 frag src (-2y)
static const size_t OFF_TGTF = 327680 + 8388608;        //   8 MB bf16 frag tgt (+y)
static const size_t OFF_S2   = 327680 + 2 * 8388608;    //  64 KB |src row|^2
static const size_t OFF_T2   = OFF_S2 + 65536;          //  64 KB |tgt row|^2
static const size_t OFF_P    = OFF_T2 + 65536;          // 1.5 MB partials (bf16 fallback)
static const size_t OFF_P2   = OFF_SRCF;                // partials (fp8; overlays dead SRCF)
static const size_t OFF_SRC8 = 18808832;                //   4 MB fp8 frag src
static const size_t OFF_TGT8 = 18808832 + 4194304;      //   4 MB fp8 frag tgt
static const size_t WS_NEED  = OFF_TGT8 + 4194304;      // ~26 MB

__device__ __forceinline__ unsigned short f2bf(float f) {
  unsigned int u = __float_as_uint(f);
  return (unsigned short)((u + 0x7FFFu + ((u >> 16) & 1u)) >> 16);  // RNE
}

__device__ __forceinline__ unsigned int pkbf(float lo, float hi) {
  unsigned int r;
  asm("v_cvt_pk_bf16_f32 %0, %1, %2" : "=v"(r) : "v"(lo), "v"(hi));
  return r;
}

// keep 3 smallest seen: t0<=t1<=t2, insert v  (1 min + 2 fmed3)
__device__ __forceinline__ void ins3(float& t0, float& t1, float& t2, float v) {
  float n0 = fminf(t0, v);
  float n1 = __builtin_amdgcn_fmed3f(t0, t1, v);
  float n2 = __builtin_amdgcn_fmed3f(t1, t2, v);
  t0 = n0; t1 = n1; t2 = n2;
}

// global -> LDS direct copy, 16 B per lane; lds dest wave-uniform base.
__device__ __forceinline__ void gload16(const void* g, void* l) {
  __builtin_amdgcn_global_load_lds(
      (const __attribute__((address_space(1))) unsigned int*)(unsigned long long)(uintptr_t)g,
      (__attribute__((address_space(3))) unsigned int*)(unsigned int)(uintptr_t)l, 16, 0, 0);
}

__device__ __forceinline__ unsigned int sxor(unsigned int v, int m) {
  return (unsigned int)__shfl_xor((int)v, m, 64);
}

// ---------------------------------------------------------------------------
// exchange: D-layout packed words -> B-frags for the next layer (K=256).
// ---------------------------------------------------------------------------
__device__ __forceinline__ void exchange8(const unsigned int* p0, const unsigned int* p1,
                                          short8* frag, int g) {
  const bool go = (g & 1), gh = (g >> 1);
#pragma unroll
  for (int ks = 0; ks < 8; ++ks) {
    unsigned int a_o = p0[2 * ks], b_o = p1[2 * ks];
    unsigned int c_o = p0[2 * ks + 1], d_o = p1[2 * ks + 1];
    unsigned int a_n = sxor(a_o, 16), b_n = sxor(b_o, 16);
    unsigned int c_n = sxor(c_o, 16), d_n = sxor(d_o, 16);
    unsigned int qab0 = go ? a_n : a_o, qab1 = go ? b_n : b_o;
    unsigned int qab2 = go ? a_o : a_n, qab3 = go ? b_o : b_n;
    unsigned int qcd0 = go ? c_n : c_o, qcd1 = go ? d_n : d_o;
    unsigned int qcd2 = go ? c_o : c_n, qcd3 = go ? d_o : d_n;
    unsigned int s0 = gh ? qab0 : qcd0, s1 = gh ? qab1 : qcd1;
    unsigned int s2 = gh ? qab2 : qcd2, s3 = gh ? qab3 : qcd3;
    unsigned int r0 = sxor(s0, 32), r1 = sxor(s1, 32);
    unsigned int r2 = sxor(s2, 32), r3 = sxor(s3, 32);
    union { unsigned int u[4]; short8 s; } cv;
    cv.u[0] = (g == 0) ? qab0 : (g == 3) ? qcd0 : r0;
    cv.u[1] = (g == 0) ? qab1 : (g == 3) ? qcd1 : r1;
    cv.u[2] = (g == 0) ? qab2 : (g == 3) ? qcd2 : r2;
    cv.u[3] = (g == 0) ? qab3 : (g == 3) ? qcd3 : r3;
    frag[ks] = cv.s;
  }
}

// ---------------------------------------------------------------------------
// prep: W[k][c] fp32 -> bf16 frag-linear (A-frag of W^T).
// ---------------------------------------------------------------------------
__global__ void prep_weights(const float* __restrict__ W1, const float* __restrict__ W2,
                             const float* __restrict__ W3, unsigned short* __restrict__ ws16) {
  int t = blockIdx.x * 256 + threadIdx.x;  // 20480 total
  const float* W;
  unsigned short* dst;
  int f, ksbits;
  if (t < 4096)       { W = W1; dst = ws16 + OFF_W1F / 2; f = t;         ksbits = 2; }
  else if (t < 12288) { W = W2; dst = ws16 + OFF_W2F / 2; f = t - 4096;  ksbits = 3; }
  else                { W = W3; dst = ws16 + OFF_W3F / 2; f = t - 12288; ksbits = 3; }
  int l  = f & 63;
  int fk = f >> 6;
  int ks = fk & ((1 << ksbits) - 1);
  int cf = fk >> ksbits;
  int k0 = ks * 32 + ((l >> 4) << 3);
  int c  = (cf << 4) + (l & 15);
  short8 v;
#pragma unroll
  for (int j = 0; j < 8; ++j) v[j] = (short)f2bf(W[(size_t)(k0 + j) * 256 + c]);
  *(short8*)(dst + (size_t)f * 8) = v;
}

// ---------------------------------------------------------------------------
// encode: unchanged from round 6 (verified, ~15 us).
// ---------------------------------------------------------------------------
__global__ __launch_bounds__(256, 2) void encode_kernel(
    const float* __restrict__ xsrc, const float* __restrict__ xtgt,
    const float* __restrict__ b1, const float* __restrict__ b2, const float* __restrict__ b3,
    const float* __restrict__ gamma, const float* __restrict__ beta,
    float* __restrict__ out_src, unsigned short* __restrict__ ws16) {
  __shared__ unsigned short wlds[2][16384];  // 2 x 32 KB
  const int tid = threadIdx.x, w = tid >> 6, l = tid & 63;
  const int dr = l & 15, g = l >> 4;
  const int blk = blockIdx.x;
  const bool is_src = blk < 256;
  const int row0 = ((blk & 255) << 6) + (w << 4);
  const int row = row0 + dr;
  const float* __restrict__ X = is_src ? xsrc : xtgt;
  unsigned short* __restrict__ fragout = ws16 + (is_src ? OFF_SRCF / 2 : OFF_TGTF / 2);
  float* __restrict__ nrm = (float*)(ws16 + (is_src ? OFF_S2 / 2 : OFF_T2 / 2));
  const unsigned short* W1f = ws16 + OFF_W1F / 2;
  const unsigned short* W2f = ws16 + OFF_W2F / 2;
  const unsigned short* W3f = ws16 + OFF_W3F / 2;

  auto stageW = [&](int bsel, int q) {
    const unsigned short* src;
    int rounds;
    if (q < 4)      { src = W1f + q * 8192;        rounds = 4; }
    else if (q < 8) { src = W2f + (q - 4) * 16384; rounds = 8; }
    else            { src = W3f + (q - 8) * 16384; rounds = 8; }
#pragma unroll
    for (int r = 0; r < 8; ++r) {
      if (r < rounds)
        gload16(src + r * 2048 + w * 512 + l * 8, &wlds[bsel][r * 2048 + w * 512]);
    }
  };

  short8 xf[4];
  const float* xr = X + (size_t)row * 128;
#pragma unroll
  for (int ks = 0; ks < 4; ++ks) {
    floatx4 f0 = *(const floatx4*)(xr + ks * 32 + g * 8);
    floatx4 f1 = *(const floatx4*)(xr + ks * 32 + g * 8 + 4);
    union { unsigned int u[4]; short8 s; } cv;
    cv.u[0] = pkbf(f0[0], f0[1]); cv.u[1] = pkbf(f0[2], f0[3]);
    cv.u[2] = pkbf(f1[0], f1[1]); cv.u[3] = pkbf(f1[2], f1[3]);
    xf[ks] = cv.s;
  }

  unsigned int p0[16], p1[16];
  short8 hf[8];

  stageW(0, 0);
  __syncthreads();
  int cur = 0;

#pragma unroll
  for (int qq = 0; qq < 4; ++qq) {
    stageW(cur ^ 1, qq + 1);
#pragma unroll
    for (int i = 0; i < 4; ++i) {
      int cf = qq * 4 + i;
      floatx4 acc = {0.f, 0.f, 0.f, 0.f};
#pragma unroll
      for (int ks = 0; ks < 4; ++ks) {
        short8 wf = *(const short8*)(&wlds[cur][((i * 4 + ks) * 64 + l) * 8]);
        acc = MFMA16(wf, xf[ks], acc);
      }
      floatx4 bv = *(const floatx4*)(b1 + cf * 16 + g * 4);
      float h0 = fmaxf(acc[0] + bv[0], 0.f), h1v = fmaxf(acc[1] + bv[1], 0.f);
      float h2v = fmaxf(acc[2] + bv[2], 0.f), h3v = fmaxf(acc[3] + bv[3], 0.f);
      p0[cf] = pkbf(h0, h1v); p1[cf] = pkbf(h2v, h3v);
    }
    __syncthreads();
    cur ^= 1;
  }
  exchange8(p0, p1, hf, g);

#pragma unroll
  for (int qq = 0; qq < 4; ++qq) {
    stageW(cur ^ 1, 5 + qq);
#pragma unroll
    for (int i = 0; i < 4; ++i) {
      int cf = qq * 4 + i;
      floatx4 acc = {0.f, 0.f, 0.f, 0.f};
#pragma unroll
      for (int ks = 0; ks < 8; ++ks) {
        short8 wf = *(const short8*)(&wlds[cur][((i * 8 + ks) * 64 + l) * 8]);
        acc = MFMA16(wf, hf[ks], acc);
      }
      floatx4 bv = *(const floatx4*)(b2 + cf * 16 + g * 4);
      float h0 = fmaxf(acc[0] + bv[0], 0.f), h1v = fmaxf(acc[1] + bv[1], 0.f);
      float h2v = fmaxf(acc[2] + bv[2], 0.f), h3v = fmaxf(acc[3] + bv[3], 0.f);
      p0[cf] = pkbf(h0, h1v); p1[cf] = pkbf(h2v, h3v);
    }
    __syncthreads();
    cur ^= 1;
  }
  exchange8(p0, p1, hf, g);

  floatx4 z[16];
#pragma unroll
  for (int qq = 0; qq < 4; ++qq) {
    if (qq < 3) stageW(cur ^ 1, 9 + qq);
#pragma unroll
    for (int i = 0; i < 4; ++i) {
      int cf = qq * 4 + i;
      floatx4 acc = {0.f, 0.f, 0.f, 0.f};
#pragma unroll
      for (int ks = 0; ks < 8; ++ks) {
        short8 wf = *(const short8*)(&wlds[cur][((i * 8 + ks) * 64 + l) * 8]);
        acc = MFMA16(wf, hf[ks], acc);
      }
      floatx4 bv = *(const floatx4*)(b3 + cf * 16 + g * 4);
#pragma unroll
      for (int j = 0; j < 4; ++j) acc[j] += bv[j];
      z[cf] = acc;
    }
    __syncthreads();
    cur ^= 1;
  }

  float s = 0.f, q = 0.f;
#pragma unroll
  for (int cf = 0; cf < 16; ++cf)
#pragma unroll
    for (int j = 0; j < 4; ++j) { float v = z[cf][j]; s += v; q = fmaf(v, v, q); }
  s += __shfl_xor(s, 16, 64); s += __shfl_xor(s, 32, 64);
  q += __shfl_xor(q, 16, 64); q += __shfl_xor(q, 32, 64);
  float mu = s * 0.00390625f;
  float var = q * 0.00390625f - mu * mu;  // biased var (torch LN)
  float rstd = rsqrtf(var + 1e-5f);

  const float sc = is_src ? -2.0f : 1.0f;
  float nacc = 0.f;
#pragma unroll
  for (int cf = 0; cf < 16; ++cf) {
    floatx4 gv = *(const floatx4*)(gamma + cf * 16 + g * 4);
    floatx4 bev = *(const floatx4*)(beta + cf * 16 + g * 4);
    float y0 = (z[cf][0] - mu) * rstd * gv[0] + bev[0];
    float y1 = (z[cf][1] - mu) * rstd * gv[1] + bev[1];
    float y2 = (z[cf][2] - mu) * rstd * gv[2] + bev[2];
    float y3 = (z[cf][3] - mu) * rstd * gv[3] + bev[3];
    nacc = fmaf(y0, y0, nacc); nacc = fmaf(y1, y1, nacc);
    nacc = fmaf(y2, y2, nacc); nacc = fmaf(y3, y3, nacc);
    p0[cf] = pkbf(sc * y0, sc * y1); p1[cf] = pkbf(sc * y2, sc * y3);
  }
  nacc += __shfl_xor(nacc, 16, 64); nacc += __shfl_xor(nacc, 32, 64);
  if (g == 0) nrm[row] = nacc;

  short8 yf[8];
  exchange8(p0, p1, yf, g);

  const int tile = row0 >> 4;
#pragma unroll
  for (int ks = 0; ks < 8; ++ks)
    *(short8*)(fragout + ((size_t)(tile * 8 + ks) * 64 + l) * 8) = yf[ks];

  if (is_src) {
    float* orow = out_src + (size_t)row * 256;
#pragma unroll
    for (int ks = 0; ks < 8; ++ks) {
      union { short8 s; unsigned int u[4]; } cv; cv.s = yf[ks];
      floatx4 o0, o1;
      o0[0] = __uint_as_float(cv.u[0] << 16) * -0.5f;
      o0[1] = __uint_as_float(cv.u[0] & 0xffff0000u) * -0.5f;
      o0[2] = __uint_as_float(cv.u[1] << 16) * -0.5f;
      o0[3] = __uint_as_float(cv.u[1] & 0xffff0000u) * -0.5f;
      o1[0] = __uint_as_float(cv.u[2] << 16) * -0.5f;
      o1[1] = __uint_as_float(cv.u[2] & 0xffff0000u) * -0.5f;
      o1[2] = __uint_as_float(cv.u[3] << 16) * -0.5f;
      o1[3] = __uint_as_float(cv.u[3] & 0xffff0000u) * -0.5f;
      *(floatx4*)(orow + ks * 32 + g * 8) = o0;
      *(floatx4*)(orow + ks * 32 + g * 8 + 4) = o1;
    }
  }
}

// ---------------------------------------------------------------------------
// repack: bf16 frag-linear -> fp8 e4m3 K=128 frag, SPLIT-HALF layout.
// ---------------------------------------------------------------------------
__global__ __launch_bounds__(256) void repack_fp8(const unsigned short* __restrict__ ws16,
                                                  unsigned char* __restrict__ wsb) {
  int t = blockIdx.x * 256 + threadIdx.x;  // 262144 total
  const int side = t >> 17;                // 0 = src, 1 = tgt
  const int u = t & 131071;
  const int df = u >> 6, l = u & 63;
  const int tile = df >> 1, ks2 = df & 1;
  const unsigned short* sbase = ws16 + (side ? OFF_TGTF / 2 : OFF_SRCF / 2);
  unsigned char* dbase = wsb + (side ? OFF_TGT8 : OFF_SRC8);
  int r[8];
#pragma unroll
  for (int sub = 0; sub < 4; ++sub) {
    int sf = (tile * 8 + ks2 * 4 + (l >> 4)) * 64 + sub * 16 + (l & 15);
    short8 v = *(const short8*)(sbase + (size_t)sf * 8);
    float f[8];
#pragma unroll
    for (int j = 0; j < 8; ++j)
      f[j] = __uint_as_float(((unsigned int)(unsigned short)v[j]) << 16);
    unsigned int w0 = __builtin_amdgcn_cvt_pk_fp8_f32(f[0], f[1], 0, 0);
    w0 = __builtin_amdgcn_cvt_pk_fp8_f32(f[2], f[3], w0, 1);
    unsigned int w1 = __builtin_amdgcn_cvt_pk_fp8_f32(f[4], f[5], 0, 0);
    w1 = __builtin_amdgcn_cvt_pk_fp8_f32(f[6], f[7], w1, 1);
    r[sub * 2] = (int)w0;
    r[sub * 2 + 1] = (int)w1;
  }
  int4v rlo = {r[0], r[1], r[2], r[3]};
  int4v rhi = {r[4], r[5], r[6], r[7]};
  *(int4v*)(dbase + (size_t)df * 2048 + l * 16) = rlo;
  *(int4v*)(dbase + (size_t)df * 2048 + 1024 + l * 16) = rhi;
}

// ---------------------------------------------------------------------------
// dist12: fp8 distance GEMM, deep private-LDS prefetch, no loop barriers.
//         grid 512 = 64 row-tiles x 8 splits; 4 waves x 64 rows (rf=4).
//         Per wave: 4 rotating 4 KB LDS frag slots; counted vmcnt(12).
// ---------------------------------------------------------------------------
__global__ __launch_bounds__(256, 2) void dist12_kernel(
    const unsigned char* __restrict__ src8, const unsigned char* __restrict__ tgt8,
    const float* __restrict__ t2, float* __restrict__ part) {
  __shared__ unsigned char fbuf[4][4][4096];  // 64 KB: [wave][slot][frag]
  __shared__ float t2l[2048];                 //  8 KB: this split's |t|^2
  const int tid = threadIdx.x, w = tid >> 6, l = tid & 63;
  const int blk = blockIdx.x;
  const int split = blk & 7;
  const int rg = (blk >> 3) * 4 + w;         // 0..255 row-group of 64
  const int R0 = rg * 64;
  const int C0 = split * 2048;

  // t2 slice -> shared LDS (one barrier, before the barrier-free main loop)
  {
    floatx4 v0 = *(const floatx4*)(t2 + C0 + tid * 8);
    floatx4 v1 = *(const floatx4*)(t2 + C0 + tid * 8 + 4);
    *(floatx4*)(t2l + tid * 8) = v0;
    *(floatx4*)(t2l + tid * 8 + 4) = v1;
  }

  // resident A: 4 row-frags x 2 K-halves (fp8, split-half layout)
  int8v a[4][2];
#pragma unroll
  for (int rf = 0; rf < 4; ++rf)
#pragma unroll
    for (int ks2 = 0; ks2 < 2; ++ks2) {
      const unsigned char* ab = src8 + ((size_t)((R0 >> 4) + rf) * 2 + ks2) * 2048;
      int4v lo = *(const int4v*)(ab + l * 16);
      int4v hi = *(const int4v*)(ab + 1024 + l * 16);
      a[rf][ks2] = cat8(lo, hi);
    }

  float t3[4][4][3];
#pragma unroll
  for (int rf = 0; rf < 4; ++rf)
#pragma unroll
    for (int j = 0; j < 4; ++j) { t3[rf][j][0] = 1e30f; t3[rf][j][1] = 1e30f; t3[rf][j][2] = 1e30f; }

  __syncthreads();  // t2l ready; no barriers after this point

  const unsigned char* gb = tgt8 + (size_t)(C0 >> 4) * 4096;  // frag c at gb + c*4096

  // stage one frag (4 KB) into this wave's LDS slot: 4 x gload16
#define STG(slot, c)                                                          \
  {                                                                           \
    const unsigned char* p = gb + (size_t)(c) * 4096 + l * 16;                \
    gload16(p,        &fbuf[w][slot][0]);                                     \
    gload16(p + 1024, &fbuf[w][slot][1024]);                                  \
    gload16(p + 2048, &fbuf[w][slot][2048]);                                  \
    gload16(p + 3072, &fbuf[w][slot][3072]);                                  \
  }

  STG(0, 0);
  STG(1, 1);
  STG(2, 2);

  for (int cc = 0; cc < 128; cc += 4) {
#pragma unroll
    for (int s = 0; s < 4; ++s) {
      const int c = cc + s;
      const int pf = (c + 3 < 128) ? (c + 3) : 127;  // tail: re-issue 127 (slot math safe)
      STG((s + 3) & 3, pf);
      asm volatile("s_waitcnt vmcnt(12)" ::: "memory");  // frag c resident (3 frags in flight)
      const unsigned char* fb = &fbuf[w][s][0];
      int4v l0 = *(const int4v*)(fb + l * 16);
      int4v h0 = *(const int4v*)(fb + 1024 + l * 16);
      int4v l1 = *(const int4v*)(fb + 2048 + l * 16);
      int4v h1 = *(const int4v*)(fb + 3072 + l * 16);
      int8v b0 = cat8(l0, h0), b1 = cat8(l1, h1);
      float tv = t2l[c * 16 + (l & 15)];
      floatx4 acc[4];
#pragma unroll
      for (int rf = 0; rf < 4; ++rf) acc[rf] = (floatx4){tv, tv, tv, tv};
      __builtin_amdgcn_s_setprio(1);
#pragma unroll
      for (int rf = 0; rf < 4; ++rf) acc[rf] = mfma8(a[rf][0], b0, acc[rf]);
#pragma unroll
      for (int rf = 0; rf < 4; ++rf) acc[rf] = mfma8(a[rf][1], b1, acc[rf]);
      __builtin_amdgcn_s_setprio(0);
#pragma unroll
      for (int rf = 0; rf < 4; ++rf)
#pragma unroll
        for (int j = 0; j < 4; ++j)
          ins3(t3[rf][j][0], t3[rf][j][1], t3[rf][j][2], acc[rf][j]);
    }
  }
#undef STG

  // merge across the 16 column-lanes (butterfly; row groups preserved)
#pragma unroll
  for (int rf = 0; rf < 4; ++rf)
#pragma unroll
    for (int j = 0; j < 4; ++j)
#pragma unroll
      for (int m = 1; m < 16; m <<= 1) {
        float o0 = __shfl_xor(t3[rf][j][0], m, 64);
        float o1 = __shfl_xor(t3[rf][j][1], m, 64);
        float o2 = __shfl_xor(t3[rf][j][2], m, 64);
        ins3(t3[rf][j][0], t3[rf][j][1], t3[rf][j][2], o0);
        ins3(t3[rf][j][0], t3[rf][j][1], t3[rf][j][2], o1);
        ins3(t3[rf][j][0], t3[rf][j][1], t3[rf][j][2], o2);
      }
  if ((l & 15) == 0) {
    int q = l >> 4;
#pragma unroll
    for (int rf = 0; rf < 4; ++rf)
#pragma unroll
      for (int j = 0; j < 4; ++j) {
        int row = R0 + rf * 16 + q * 4 + j;
        float* p = part + ((size_t)row * 8 + split) * 3;
        p[0] = t3[rf][j][0];
        p[1] = t3[rf][j][1];
        p[2] = t3[rf][j][2];
      }
  }
}

// ---------------------------------------------------------------------------
// dist (bf16 fallback, round-4 verified): used only if ws_size < WS_NEED.
// ---------------------------------------------------------------------------
__global__ __launch_bounds__(512, 2) void dist_kernel(
    const unsigned short* __restrict__ srcf, const unsigned short* __restrict__ tgtf,
    const float* __restrict__ t2, float* __restrict__ part) {
  __shared__ unsigned short buf[2][32768];  // 2 x 64 KB
  const int tid = threadIdx.x, w = tid >> 6, l = tid & 63;
  const int blk = blockIdx.x;
  const int split = blk & 7;
  const int rtile = blk >> 3;
  const int R0 = rtile * 512 + w * 64;
  const int C0 = split * 2048;

  short8 a[4][8];
#pragma unroll
  for (int rf = 0; rf < 4; ++rf)
#pragma unroll
    for (int ks = 0; ks < 8; ++ks)
      a[rf][ks] = *(const short8*)(srcf + (((size_t)(R0 / 16 + rf) * 8 + ks) * 64 + l) * 8);

  float t3[4][4][3];
#pragma unroll
  for (int rf = 0; rf < 4; ++rf)
#pragma unroll
    for (int j = 0; j < 4; ++j) { t3[rf][j][0] = 1e30f; t3[rf][j][1] = 1e30f; t3[rf][j][2] = 1e30f; }

  const unsigned short* gb0 = tgtf + (size_t)(C0 / 16) * 4096;
#define STAGE(bsel, t)                                                        \
  {                                                                           \
    const unsigned short* gb = gb0 + (size_t)(t) * 32768;                     \
    _Pragma("unroll") for (int i = 0; i < 8; ++i) {                           \
      int chunk = w * 8 + i;                                                  \
      gload16(gb + chunk * 512 + l * 8, &buf[bsel][chunk * 512]);             \
    }                                                                         \
  }

  STAGE(0, 0);
  float t2v[8];
#pragma unroll
  for (int c = 0; c < 8; ++c) t2v[c] = t2[C0 + c * 16 + (l & 15)];
  __syncthreads();

  for (int t = 0; t < 16; ++t) {
    int cur = t & 1;
    if (t < 15) STAGE(cur ^ 1, t + 1);
    float t2n[8];
    if (t < 15) {
      int nb = C0 + (t + 1) * 128;
#pragma unroll
      for (int c = 0; c < 8; ++c) t2n[c] = t2[nb + c * 16 + (l & 15)];
    }
#pragma unroll
    for (int cf = 0; cf < 8; ++cf) {
      const unsigned short* bb = &buf[cur][cf << 12];
      float tv = t2v[cf];
      floatx4 acc[4];
      short8 bc = *(const short8*)(bb + l * 8);
#pragma unroll
      for (int rf = 0; rf < 4; ++rf) acc[rf] = (floatx4){tv, tv, tv, tv};
      __builtin_amdgcn_s_setprio(1);
#pragma unroll
      for (int ks = 0; ks < 8; ++ks) {
        short8 bn = bc;
        if (ks < 7) bn = *(const short8*)(bb + (ks + 1) * 512 + l * 8);
#pragma unroll
        for (int rf = 0; rf < 4; ++rf) acc[rf] = MFMA16(a[rf][ks], bc, acc[rf]);
        bc = bn;
      }
      __builtin_amdgcn_s_setprio(0);
#pragma unroll
      for (int rf = 0; rf < 4; ++rf)
#pragma unroll
        for (int j = 0; j < 4; ++j)
          ins3(t3[rf][j][0], t3[rf][j][1], t3[rf][j][2], acc[rf][j]);
    }
#pragma unroll
    for (int c = 0; c < 8; ++c) t2v[c] = t2n[c];
    __syncthreads();
  }
#undef STAGE

#pragma unroll
  for (int rf = 0; rf < 4; ++rf)
#pragma unroll
    for (int j = 0; j < 4; ++j)
#pragma unroll
      for (int m = 1; m < 16; m <<= 1) {
        float o0 = __shfl_xor(t3[rf][j][0], m, 64);
        float o1 = __shfl_xor(t3[rf][j][1], m, 64);
        float o2 = __shfl_xor(t3[rf][j][2], m, 64);
        ins3(t3[rf][j][0], t3[rf][j][1], t3[rf][j][2], o0);
        ins3(t3[rf][j][0], t3[rf][j][1], t3[rf][j][2], o1);
        ins3(t3[rf][j][0], t3[rf][j][1], t3[rf][j][2], o2);
      }
  if ((l & 15) == 0) {
    int q = l >> 4;
#pragma unroll
    for (int rf = 0; rf < 4; ++rf)
#pragma unroll
      for (int j = 0; j < 4; ++j) {
        int row = R0 + rf * 16 + q * 4 + j;
        float* p = part + ((size_t)row * 8 + split) * 3;
        p[0] = t3[rf][j][0];
        p[1] = t3[rf][j][1];
        p[2] = t3[rf][j][2];
      }
  }
}

// ---------------------------------------------------------------------------
// merge: per row fold ncand candidates, add |s|^2, sqrt, entropy.
// ---------------------------------------------------------------------------
__global__ void merge_kernel(const float* __restrict__ part, const float* __restrict__ s2,
                             float* __restrict__ eout, int ncand) {
  int r = blockIdx.x * 256 + threadIdx.x;  // 16384
  const float* p = part + (size_t)r * ncand;
  float u0 = 1e30f, u1 = 1e30f, u2 = 1e30f;
  for (int i = 0; i < ncand; ++i) ins3(u0, u1, u2, p[i]);
  float sv = s2[r];
  float d0 = sqrtf(fmaxf(sv + u0, 0.f));
  float d1 = sqrtf(fmaxf(sv + u1, 0.f));
  float d2 = sqrtf(fmaxf(sv + u2, 0.f));
  eout[r] = (d0 + d1 + d2) * 0.5f;
}

extern "C" void kernel_launch(void* const* d_in, const int* in_sizes, int n_in,
                              void* d_out, int out_size, void* d_ws, size_t ws_size,
                              hipStream_t stream) {
  const float* xsrc = (const float*)d_in[0];
  const float* xtgt = (const float*)d_in[1];
  const float* W1 = (const float*)d_in[2];
  const float* b1 = (const float*)d_in[3];
  const float* W2 = (const float*)d_in[4];
  const float* b2 = (const float*)d_in[5];
  const float* W3 = (const float*)d_in[6];
  const float* b3 = (const float*)d_in[7];
  const float* gm = (const float*)d_in[8];
  const float* bt = (const float*)d_in[9];
  float* out = (float*)d_out;
  unsigned short* ws16 = (unsigned short*)d_ws;
  unsigned char* wsb = (unsigned char*)d_ws;

  prep_weights<<<80, 256, 0, stream>>>(W1, W2, W3, ws16);
  encode_kernel<<<512, 256, 0, stream>>>(xsrc, xtgt, b1, b2, b3, gm, bt, out, ws16);
  if (ws_size >= WS_NEED) {
    repack_fp8<<<1024, 256, 0, stream>>>(ws16, wsb);
    dist12_kernel<<<512, 256, 0, stream>>>(wsb + OFF_SRC8, wsb + OFF_TGT8,
                                           (const float*)(wsb + OFF_T2),
                                           (float*)(wsb + OFF_P2));
    merge_kernel<<<64, 256, 0, stream>>>((const float*)(wsb + OFF_P2),
                                         (const float*)(wsb + OFF_S2),
                                         out + 4194304, 24);
  } else {
    dist_kernel<<<256, 512, 0, stream>>>(ws16 + OFF_SRCF / 2, ws16 + OFF_TGTF / 2,
                                         (const float*)(wsb + OFF_T2),
                                         (float*)(wsb + OFF_P));
    merge_kernel<<<64, 256, 0, stream>>>((const float*)(wsb + OFF_P),
                                         (const float*)(wsb + OFF_S2),
                                         out + 4194304, 24);
  }
}

// Round 13
// 120.346 us; speedup vs baseline: 1.0984x; 1.0984x over previous
//
#include <hip/hip_runtime.h>
#include <math.h>

// ============================================================================
// re3: MLP-encode (3 layers + LayerNorm) of src/tgt, then fused
//      all-pairs-L2-distance + top-3-smallest + sum/2 ("state entropy").
//
// Round-13: REVERT dist to the round-8 best-measured variant (88.0 us).
//   Six structural variants (r7-r12) all plateau 88-96 us at MfmaUtil ~33%;
//   the r8 config (4 waves x 64 rows, conflict-free split-half fp8 frags,
//   2 x 32 KB LDS dbuf, t2 in LDS, 2 blocks/CU) is the measured optimum.
//   dist = 1.56 PF effective fp8 — parity with the best-known plain-HIP
//   GEMM schedule on MI355X; remaining gap is the 2-wave/SIMD dependency
//   stall capped by the unified VGPR/AGPR file.
// encode / prep / repack / merge / bf16-fallback unchanged (verified).
// ============================================================================

typedef __attribute__((ext_vector_type(8))) short short8;
typedef __attribute__((ext_vector_type(4))) float floatx4;
typedef __attribute__((ext_vector_type(8))) int int8v;
typedef __attribute__((ext_vector_type(4))) int int4v;

#define MFMA16(a, b, c) __builtin_amdgcn_mfma_f32_16x16x32_bf16((a), (b), (c), 0, 0, 0)

__device__ __forceinline__ floatx4 mfma8(int8v a, int8v b, floatx4 c) {
  // fmt 0 = OCP e4m3 both operands; scale byte 127 = 2^0.
  return __builtin_amdgcn_mfma_scale_f32_16x16x128_f8f6f4(a, b, c, 0, 0, 0, 0x7F, 0, 0x7F);
}

__device__ __forceinline__ int8v cat8(int4v lo, int4v hi) {
  return __builtin_shufflevector(lo, hi, 0, 1, 2, 3, 4, 5, 6, 7);
}

// ---- ws layout (bytes) ----
static const size_t OFF_W1F  = 0;                       //  64 KB
static const size_t OFF_W2F  = 65536;                   // 128 KB
static const size_t OFF_W3F  = 196608;                  // 128 KB
static const size_t OFF_SRCF = 327680;                  //   8 MB bf16 frag src (-2y)
static const size_t OFF_TGTF = 327680 + 8388608;        //   8 MB bf16 frag tgt (+y)
static const size_t OFF_S2   = 327680 + 2 * 8388608;    //  64 KB |src row|^2
static const size_t OFF_T2   = OFF_S2 + 65536;          //  64 KB |tgt row|^2
static const size_t OFF_P    = OFF_T2 + 65536;          // 1.5 MB partial top-3
static const size_t OFF_SRC8 = 18808832;                //   4 MB fp8 frag src
static const size_t OFF_TGT8 = 18808832 + 4194304;      //   4 MB fp8 frag tgt
static const size_t WS_NEED  = OFF_TGT8 + 4194304;      // ~26 MB

__device__ __forceinline__ unsigned short f2bf(float f) {
  unsigned int u = __float_as_uint(f);
  return (unsigned short)((u + 0x7FFFu + ((u >> 16) & 1u)) >> 16);  // RNE
}

__device__ __forceinline__ unsigned int pkbf(float lo, float hi) {
  unsigned int r;
  asm("v_cvt_pk_bf16_f32 %0, %1, %2" : "=v"(r) : "v"(lo), "v"(hi));
  return r;
}

// keep 3 smallest seen: t0<=t1<=t2, insert v  (1 min + 2 fmed3)
__device__ __forceinline__ void ins3(float& t0, float& t1, float& t2, float v) {
  float n0 = fminf(t0, v);
  float n1 = __builtin_amdgcn_fmed3f(t0, t1, v);
  float n2 = __builtin_amdgcn_fmed3f(t1, t2, v);
  t0 = n0; t1 = n1; t2 = n2;
}

// global -> LDS direct copy, 16 B per lane; lds dest wave-uniform base.
__device__ __forceinline__ void gload16(const void* g, void* l) {
  __builtin_amdgcn_global_load_lds(
      (const __attribute__((address_space(1))) unsigned int*)(unsigned long long)(uintptr_t)g,
      (__attribute__((address_space(3))) unsigned int*)(unsigned int)(uintptr_t)l, 16, 0, 0);
}

__device__ __forceinline__ unsigned int sxor(unsigned int v, int m) {
  return (unsigned int)__shfl_xor((int)v, m, 64);
}

// ---------------------------------------------------------------------------
// exchange: D-layout packed words -> B-frags for the next layer (K=256).
// ---------------------------------------------------------------------------
__device__ __forceinline__ void exchange8(const unsigned int* p0, const unsigned int* p1,
                                          short8* frag, int g) {
  const bool go = (g & 1), gh = (g >> 1);
#pragma unroll
  for (int ks = 0; ks < 8; ++ks) {
    unsigned int a_o = p0[2 * ks], b_o = p1[2 * ks];
    unsigned int c_o = p0[2 * ks + 1], d_o = p1[2 * ks + 1];
    unsigned int a_n = sxor(a_o, 16), b_n = sxor(b_o, 16);
    unsigned int c_n = sxor(c_o, 16), d_n = sxor(d_o, 16);
    unsigned int qab0 = go ? a_n : a_o, qab1 = go ? b_n : b_o;
    unsigned int qab2 = go ? a_o : a_n, qab3 = go ? b_o : b_n;
    unsigned int qcd0 = go ? c_n : c_o, qcd1 = go ? d_n : d_o;
    unsigned int qcd2 = go ? c_o : c_n, qcd3 = go ? d_o : d_n;
    unsigned int s0 = gh ? qab0 : qcd0, s1 = gh ? qab1 : qcd1;
    unsigned int s2 = gh ? qab2 : qcd2, s3 = gh ? qab3 : qcd3;
    unsigned int r0 = sxor(s0, 32), r1 = sxor(s1, 32);
    unsigned int r2 = sxor(s2, 32), r3 = sxor(s3, 32);
    union { unsigned int u[4]; short8 s; } cv;
    cv.u[0] = (g == 0) ? qab0 : (g == 3) ? qcd0 : r0;
    cv.u[1] = (g == 0) ? qab1 : (g == 3) ? qcd1 : r1;
    cv.u[2] = (g == 0) ? qab2 : (g == 3) ? qcd2 : r2;
    cv.u[3] = (g == 0) ? qab3 : (g == 3) ? qcd3 : r3;
    frag[ks] = cv.s;
  }
}

// ---------------------------------------------------------------------------
// prep: W[k][c] fp32 -> bf16 frag-linear (A-frag of W^T).
// ---------------------------------------------------------------------------
__global__ void prep_weights(const float* __restrict__ W1, const float* __restrict__ W2,
                             const float* __restrict__ W3, unsigned short* __restrict__ ws16) {
  int t = blockIdx.x * 256 + threadIdx.x;  // 20480 total
  const float* W;
  unsigned short* dst;
  int f, ksbits;
  if (t < 4096)       { W = W1; dst = ws16 + OFF_W1F / 2; f = t;         ksbits = 2; }
  else if (t < 12288) { W = W2; dst = ws16 + OFF_W2F / 2; f = t - 4096;  ksbits = 3; }
  else                { W = W3; dst = ws16 + OFF_W3F / 2; f = t - 12288; ksbits = 3; }
  int l  = f & 63;
  int fk = f >> 6;
  int ks = fk & ((1 << ksbits) - 1);
  int cf = fk >> ksbits;
  int k0 = ks * 32 + ((l >> 4) << 3);
  int c  = (cf << 4) + (l & 15);
  short8 v;
#pragma unroll
  for (int j = 0; j < 8; ++j) v[j] = (short)f2bf(W[(size_t)(k0 + j) * 256 + c]);
  *(short8*)(dst + (size_t)f * 8) = v;
}

// ---------------------------------------------------------------------------
// encode: unchanged from round 6 (verified, ~15 us).
// ---------------------------------------------------------------------------
__global__ __launch_bounds__(256, 2) void encode_kernel(
    const float* __restrict__ xsrc, const float* __restrict__ xtgt,
    const float* __restrict__ b1, const float* __restrict__ b2, const float* __restrict__ b3,
    const float* __restrict__ gamma, const float* __restrict__ beta,
    float* __restrict__ out_src, unsigned short* __restrict__ ws16) {
  __shared__ unsigned short wlds[2][16384];  // 2 x 32 KB
  const int tid = threadIdx.x, w = tid >> 6, l = tid & 63;
  const int dr = l & 15, g = l >> 4;
  const int blk = blockIdx.x;
  const bool is_src = blk < 256;
  const int row0 = ((blk & 255) << 6) + (w << 4);
  const int row = row0 + dr;
  const float* __restrict__ X = is_src ? xsrc : xtgt;
  unsigned short* __restrict__ fragout = ws16 + (is_src ? OFF_SRCF / 2 : OFF_TGTF / 2);
  float* __restrict__ nrm = (float*)(ws16 + (is_src ? OFF_S2 / 2 : OFF_T2 / 2));
  const unsigned short* W1f = ws16 + OFF_W1F / 2;
  const unsigned short* W2f = ws16 + OFF_W2F / 2;
  const unsigned short* W3f = ws16 + OFF_W3F / 2;

  auto stageW = [&](int bsel, int q) {
    const unsigned short* src;
    int rounds;
    if (q < 4)      { src = W1f + q * 8192;        rounds = 4; }
    else if (q < 8) { src = W2f + (q - 4) * 16384; rounds = 8; }
    else            { src = W3f + (q - 8) * 16384; rounds = 8; }
#pragma unroll
    for (int r = 0; r < 8; ++r) {
      if (r < rounds)
        gload16(src + r * 2048 + w * 512 + l * 8, &wlds[bsel][r * 2048 + w * 512]);
    }
  };

  short8 xf[4];
  const float* xr = X + (size_t)row * 128;
#pragma unroll
  for (int ks = 0; ks < 4; ++ks) {
    floatx4 f0 = *(const floatx4*)(xr + ks * 32 + g * 8);
    floatx4 f1 = *(const floatx4*)(xr + ks * 32 + g * 8 + 4);
    union { unsigned int u[4]; short8 s; } cv;
    cv.u[0] = pkbf(f0[0], f0[1]); cv.u[1] = pkbf(f0[2], f0[3]);
    cv.u[2] = pkbf(f1[0], f1[1]); cv.u[3] = pkbf(f1[2], f1[3]);
    xf[ks] = cv.s;
  }

  unsigned int p0[16], p1[16];
  short8 hf[8];

  stageW(0, 0);
  __syncthreads();
  int cur = 0;

#pragma unroll
  for (int qq = 0; qq < 4; ++qq) {
    stageW(cur ^ 1, qq + 1);
#pragma unroll
    for (int i = 0; i < 4; ++i) {
      int cf = qq * 4 + i;
      floatx4 acc = {0.f, 0.f, 0.f, 0.f};
#pragma unroll
      for (int ks = 0; ks < 4; ++ks) {
        short8 wf = *(const short8*)(&wlds[cur][((i * 4 + ks) * 64 + l) * 8]);
        acc = MFMA16(wf, xf[ks], acc);
      }
      floatx4 bv = *(const floatx4*)(b1 + cf * 16 + g * 4);
      float h0 = fmaxf(acc[0] + bv[0], 0.f), h1v = fmaxf(acc[1] + bv[1], 0.f);
      float h2v = fmaxf(acc[2] + bv[2], 0.f), h3v = fmaxf(acc[3] + bv[3], 0.f);
      p0[cf] = pkbf(h0, h1v); p1[cf] = pkbf(h2v, h3v);
    }
    __syncthreads();
    cur ^= 1;
  }
  exchange8(p0, p1, hf, g);

#pragma unroll
  for (int qq = 0; qq < 4; ++qq) {
    stageW(cur ^ 1, 5 + qq);
#pragma unroll
    for (int i = 0; i < 4; ++i) {
      int cf = qq * 4 + i;
      floatx4 acc = {0.f, 0.f, 0.f, 0.f};
#pragma unroll
      for (int ks = 0; ks < 8; ++ks) {
        short8 wf = *(const short8*)(&wlds[cur][((i * 8 + ks) * 64 + l) * 8]);
        acc = MFMA16(wf, hf[ks], acc);
      }
      floatx4 bv = *(const floatx4*)(b2 + cf * 16 + g * 4);
      float h0 = fmaxf(acc[0] + bv[0], 0.f), h1v = fmaxf(acc[1] + bv[1], 0.f);
      float h2v = fmaxf(acc[2] + bv[2], 0.f), h3v = fmaxf(acc[3] + bv[3], 0.f);
      p0[cf] = pkbf(h0, h1v); p1[cf] = pkbf(h2v, h3v);
    }
    __syncthreads();
    cur ^= 1;
  }
  exchange8(p0, p1, hf, g);

  floatx4 z[16];
#pragma unroll
  for (int qq = 0; qq < 4; ++qq) {
    if (qq < 3) stageW(cur ^ 1, 9 + qq);
#pragma unroll
    for (int i = 0; i < 4; ++i) {
      int cf = qq * 4 + i;
      floatx4 acc = {0.f, 0.f, 0.f, 0.f};
#pragma unroll
      for (int ks = 0; ks < 8; ++ks) {
        short8 wf = *(const short8*)(&wlds[cur][((i * 8 + ks) * 64 + l) * 8]);
        acc = MFMA16(wf, hf[ks], acc);
      }
      floatx4 bv = *(const floatx4*)(b3 + cf * 16 + g * 4);
#pragma unroll
      for (int j = 0; j < 4; ++j) acc[j] += bv[j];
      z[cf] = acc;
    }
    __syncthreads();
    cur ^= 1;
  }

  float s = 0.f, q = 0.f;
#pragma unroll
  for (int cf = 0; cf < 16; ++cf)
#pragma unroll
    for (int j = 0; j < 4; ++j) { float v = z[cf][j]; s += v; q = fmaf(v, v, q); }
  s += __shfl_xor(s, 16, 64); s += __shfl_xor(s, 32, 64);
  q += __shfl_xor(q, 16, 64); q += __shfl_xor(q, 32, 64);
  float mu = s * 0.00390625f;
  float var = q * 0.00390625f - mu * mu;  // biased var (torch LN)
  float rstd = rsqrtf(var + 1e-5f);

  const float sc = is_src ? -2.0f : 1.0f;
  float nacc = 0.f;
#pragma unroll
  for (int cf = 0; cf < 16; ++cf) {
    floatx4 gv = *(const floatx4*)(gamma + cf * 16 + g * 4);
    floatx4 bev = *(const floatx4*)(beta + cf * 16 + g * 4);
    float y0 = (z[cf][0] - mu) * rstd * gv[0] + bev[0];
    float y1 = (z[cf][1] - mu) * rstd * gv[1] + bev[1];
    float y2 = (z[cf][2] - mu) * rstd * gv[2] + bev[2];
    float y3 = (z[cf][3] - mu) * rstd * gv[3] + bev[3];
    nacc = fmaf(y0, y0, nacc); nacc = fmaf(y1, y1, nacc);
    nacc = fmaf(y2, y2, nacc); nacc = fmaf(y3, y3, nacc);
    p0[cf] = pkbf(sc * y0, sc * y1); p1[cf] = pkbf(sc * y2, sc * y3);
  }
  nacc += __shfl_xor(nacc, 16, 64); nacc += __shfl_xor(nacc, 32, 64);
  if (g == 0) nrm[row] = nacc;

  short8 yf[8];
  exchange8(p0, p1, yf, g);

  const int tile = row0 >> 4;
#pragma unroll
  for (int ks = 0; ks < 8; ++ks)
    *(short8*)(fragout + ((size_t)(tile * 8 + ks) * 64 + l) * 8) = yf[ks];

  if (is_src) {
    float* orow = out_src + (size_t)row * 256;
#pragma unroll
    for (int ks = 0; ks < 8; ++ks) {
      union { short8 s; unsigned int u[4]; } cv; cv.s = yf[ks];
      floatx4 o0, o1;
      o0[0] = __uint_as_float(cv.u[0] << 16) * -0.5f;
      o0[1] = __uint_as_float(cv.u[0] & 0xffff0000u) * -0.5f;
      o0[2] = __uint_as_float(cv.u[1] << 16) * -0.5f;
      o0[3] = __uint_as_float(cv.u[1] & 0xffff0000u) * -0.5f;
      o1[0] = __uint_as_float(cv.u[2] << 16) * -0.5f;
      o1[1] = __uint_as_float(cv.u[2] & 0xffff0000u) * -0.5f;
      o1[2] = __uint_as_float(cv.u[3] << 16) * -0.5f;
      o1[3] = __uint_as_float(cv.u[3] & 0xffff0000u) * -0.5f;
      *(floatx4*)(orow + ks * 32 + g * 8) = o0;
      *(floatx4*)(orow + ks * 32 + g * 8 + 4) = o1;
    }
  }
}

// ---------------------------------------------------------------------------
// repack: bf16 frag-linear -> fp8 e4m3 K=128 frag, SPLIT-HALF layout:
//   frag df at dbase+df*2048: bytes 0-15 of all 64 lanes (lane-contiguous),
//   then (+1024) bytes 16-31. byte j of lane l <-> row l&15, k=(l>>4)*32+j.
// ---------------------------------------------------------------------------
__global__ __launch_bounds__(256) void repack_fp8(const unsigned short* __restrict__ ws16,
                                                  unsigned char* __restrict__ wsb) {
  int t = blockIdx.x * 256 + threadIdx.x;  // 262144 total
  const int side = t >> 17;                // 0 = src, 1 = tgt
  const int u = t & 131071;
  const int df = u >> 6, l = u & 63;
  const int tile = df >> 1, ks2 = df & 1;
  const unsigned short* sbase = ws16 + (side ? OFF_TGTF / 2 : OFF_SRCF / 2);
  unsigned char* dbase = wsb + (side ? OFF_TGT8 : OFF_SRC8);
  int r[8];
#pragma unroll
  for (int sub = 0; sub < 4; ++sub) {
    int sf = (tile * 8 + ks2 * 4 + (l >> 4)) * 64 + sub * 16 + (l & 15);
    short8 v = *(const short8*)(sbase + (size_t)sf * 8);
    float f[8];
#pragma unroll
    for (int j = 0; j < 8; ++j)
      f[j] = __uint_as_float(((unsigned int)(unsigned short)v[j]) << 16);
    unsigned int w0 = __builtin_amdgcn_cvt_pk_fp8_f32(f[0], f[1], 0, 0);
    w0 = __builtin_amdgcn_cvt_pk_fp8_f32(f[2], f[3], w0, 1);
    unsigned int w1 = __builtin_amdgcn_cvt_pk_fp8_f32(f[4], f[5], 0, 0);
    w1 = __builtin_amdgcn_cvt_pk_fp8_f32(f[6], f[7], w1, 1);
    r[sub * 2] = (int)w0;
    r[sub * 2 + 1] = (int)w1;
  }
  int4v rlo = {r[0], r[1], r[2], r[3]};
  int4v rhi = {r[4], r[5], r[6], r[7]};
  *(int4v*)(dbase + (size_t)df * 2048 + l * 16) = rlo;
  *(int4v*)(dbase + (size_t)df * 2048 + 1024 + l * 16) = rhi;
}

// ---------------------------------------------------------------------------
// dist8: MX-fp8 distance GEMM (round-8 best: 88.0 us). grid 512 = 64 row-
//        tiles x 8 col-splits; 256-thread blocks (4 waves x 64 rows, rf=4),
//        2 blocks/CU. 16 tiles of 128 cols, 2 x 32 KB LDS dbuf, split-half
//        frag layout (conflict-free b128 reads), t2 in LDS.
// ---------------------------------------------------------------------------
__global__ __launch_bounds__(256, 2) void dist8_kernel(
    const unsigned char* __restrict__ src8, const unsigned char* __restrict__ tgt8,
    const float* __restrict__ t2, float* __restrict__ part) {
  __shared__ unsigned char buf[2][32768];  // 2 x 32 KB
  __shared__ float t2l[2048];              // 8 KB: this split's |t|^2 slice
  const int tid = threadIdx.x, w = tid >> 6, l = tid & 63;
  const int blk = blockIdx.x;
  const int split = blk & 7;
  const int rtile = blk >> 3;              // 0..63
  const int R0 = rtile * 256 + w * 64;
  const int C0 = split * 2048;

  // t2 slice -> LDS
  {
    floatx4 v0 = *(const floatx4*)(t2 + C0 + tid * 8);
    floatx4 v1 = *(const floatx4*)(t2 + C0 + tid * 8 + 4);
    *(floatx4*)(t2l + tid * 8) = v0;
    *(floatx4*)(t2l + tid * 8 + 4) = v1;
  }

  // resident A: 4 row-frags x 2 K-halves (fp8, split-half layout)
  int8v a[4][2];
#pragma unroll
  for (int rf = 0; rf < 4; ++rf)
#pragma unroll
    for (int ks2 = 0; ks2 < 2; ++ks2) {
      const unsigned char* ab = src8 + ((size_t)((R0 >> 4) + rf) * 2 + ks2) * 2048;
      int4v lo = *(const int4v*)(ab + l * 16);
      int4v hi = *(const int4v*)(ab + 1024 + l * 16);
      a[rf][ks2] = cat8(lo, hi);
    }

  float t3[4][4][3];
#pragma unroll
  for (int rf = 0; rf < 4; ++rf)
#pragma unroll
    for (int j = 0; j < 4; ++j) { t3[rf][j][0] = 1e30f; t3[rf][j][1] = 1e30f; t3[rf][j][2] = 1e30f; }

  // one 128-col tile = 32 KB = 32 chunks of 1 KB; wave w stages 8 chunks
  const unsigned char* gb0 = tgt8 + (size_t)(C0 >> 4) * 4096;
#define STAGE(bsel, t)                                                        \
  {                                                                           \
    const unsigned char* gb = gb0 + (size_t)(t) * 32768;                      \
    _Pragma("unroll") for (int i = 0; i < 8; ++i) {                           \
      int chunk = w * 8 + i;                                                  \
      gload16(gb + chunk * 1024 + l * 16, &buf[bsel][chunk * 1024]);          \
    }                                                                         \
  }

  STAGE(0, 0);
  __syncthreads();

  for (int t = 0; t < 16; ++t) {
    int cur = t & 1;
    if (t < 15) STAGE(cur ^ 1, t + 1);
#pragma unroll
    for (int cf = 0; cf < 8; ++cf) {
      const unsigned char* bb = &buf[cur][cf * 4096];
      int4v l0 = *(const int4v*)(bb + l * 16);
      int4v h0 = *(const int4v*)(bb + 1024 + l * 16);
      int4v l1 = *(const int4v*)(bb + 2048 + l * 16);
      int4v h1 = *(const int4v*)(bb + 3072 + l * 16);
      int8v b0 = cat8(l0, h0), b1 = cat8(l1, h1);
      float tv = t2l[t * 128 + cf * 16 + (l & 15)];
      floatx4 acc[4];
#pragma unroll
      for (int rf = 0; rf < 4; ++rf) acc[rf] = (floatx4){tv, tv, tv, tv};
      __builtin_amdgcn_s_setprio(1);
#pragma unroll
      for (int rf = 0; rf < 4; ++rf) acc[rf] = mfma8(a[rf][0], b0, acc[rf]);
#pragma unroll
      for (int rf = 0; rf < 4; ++rf) acc[rf] = mfma8(a[rf][1], b1, acc[rf]);
      __builtin_amdgcn_s_setprio(0);
#pragma unroll
      for (int rf = 0; rf < 4; ++rf)
#pragma unroll
        for (int j = 0; j < 4; ++j)
          ins3(t3[rf][j][0], t3[rf][j][1], t3[rf][j][2], acc[rf][j]);
    }
    __syncthreads();
  }
#undef STAGE

  // merge across the 16 column-lanes (butterfly; row groups preserved)
#pragma unroll
  for (int rf = 0; rf < 4; ++rf)
#pragma unroll
    for (int j = 0; j < 4; ++j)
#pragma unroll
      for (int m = 1; m < 16; m <<= 1) {
        float o0 = __shfl_xor(t3[rf][j][0], m, 64);
        float o1 = __shfl_xor(t3[rf][j][1], m, 64);
        float o2 = __shfl_xor(t3[rf][j][2], m, 64);
        ins3(t3[rf][j][0], t3[rf][j][1], t3[rf][j][2], o0);
        ins3(t3[rf][j][0], t3[rf][j][1], t3[rf][j][2], o1);
        ins3(t3[rf][j][0], t3[rf][j][1], t3[rf][j][2], o2);
      }
  if ((l & 15) == 0) {
    int q = l >> 4;
#pragma unroll
    for (int rf = 0; rf < 4; ++rf)
#pragma unroll
      for (int j = 0; j < 4; ++j) {
        int row = R0 + rf * 16 + q * 4 + j;
        float* p = part + ((size_t)row * 8 + split) * 3;
        p[0] = t3[rf][j][0];
        p[1] = t3[rf][j][1];
        p[2] = t3[rf][j][2];
      }
  }
}

// ---------------------------------------------------------------------------
// dist (bf16 fallback, round-4 verified): used only if ws_size < WS_NEED.
// ---------------------------------------------------------------------------
__global__ __launch_bounds__(512, 2) void dist_kernel(
    const unsigned short* __restrict__ srcf, const unsigned short* __restrict__ tgtf,
    const float* __restrict__ t2, float* __restrict__ part) {
  __shared__ unsigned short buf[2][32768];  // 2 x 64 KB
  const int tid = threadIdx.x, w = tid >> 6, l = tid & 63;
  const int blk = blockIdx.x;
  const int split = blk & 7;
  const int rtile = blk >> 3;
  const int R0 = rtile * 512 + w * 64;
  const int C0 = split * 2048;

  short8 a[4][8];
#pragma unroll
  for (int rf = 0; rf < 4; ++rf)
#pragma unroll
    for (int ks = 0; ks < 8; ++ks)
      a[rf][ks] = *(const short8*)(srcf + (((size_t)(R0 / 16 + rf) * 8 + ks) * 64 + l) * 8);

  float t3[4][4][3];
#pragma unroll
  for (int rf = 0; rf < 4; ++rf)
#pragma unroll
    for (int j = 0; j < 4; ++j) { t3[rf][j][0] = 1e30f; t3[rf][j][1] = 1e30f; t3[rf][j][2] = 1e30f; }

  const unsigned short* gb0 = tgtf + (size_t)(C0 / 16) * 4096;
#define STAGE(bsel, t)                                                        \
  {                                                                           \
    const unsigned short* gb = gb0 + (size_t)(t) * 32768;                     \
    _Pragma("unroll") for (int i = 0; i < 8; ++i) {                           \
      int chunk = w * 8 + i;                                                  \
      gload16(gb + chunk * 512 + l * 8, &buf[bsel][chunk * 512]);             \
    }                                                                         \
  }

  STAGE(0, 0);
  float t2v[8];
#pragma unroll
  for (int c = 0; c < 8; ++c) t2v[c] = t2[C0 + c * 16 + (l & 15)];
  __syncthreads();

  for (int t = 0; t < 16; ++t) {
    int cur = t & 1;
    if (t < 15) STAGE(cur ^ 1, t + 1);
    float t2n[8];
    if (t < 15) {
      int nb = C0 + (t + 1) * 128;
#pragma unroll
      for (int c = 0; c < 8; ++c) t2n[c] = t2[nb + c * 16 + (l & 15)];
    }
#pragma unroll
    for (int cf = 0; cf < 8; ++cf) {
      const unsigned short* bb = &buf[cur][cf << 12];
      float tv = t2v[cf];
      floatx4 acc[4];
      short8 bc = *(const short8*)(bb + l * 8);
#pragma unroll
      for (int rf = 0; rf < 4; ++rf) acc[rf] = (floatx4){tv, tv, tv, tv};
      __builtin_amdgcn_s_setprio(1);
#pragma unroll
      for (int ks = 0; ks < 8; ++ks) {
        short8 bn = bc;
        if (ks < 7) bn = *(const short8*)(bb + (ks + 1) * 512 + l * 8);
#pragma unroll
        for (int rf = 0; rf < 4; ++rf) acc[rf] = MFMA16(a[rf][ks], bc, acc[rf]);
        bc = bn;
      }
      __builtin_amdgcn_s_setprio(0);
#pragma unroll
      for (int rf = 0; rf < 4; ++rf)
#pragma unroll
        for (int j = 0; j < 4; ++j)
          ins3(t3[rf][j][0], t3[rf][j][1], t3[rf][j][2], acc[rf][j]);
    }
#pragma unroll
    for (int c = 0; c < 8; ++c) t2v[c] = t2n[c];
    __syncthreads();
  }
#undef STAGE

#pragma unroll
  for (int rf = 0; rf < 4; ++rf)
#pragma unroll
    for (int j = 0; j < 4; ++j)
#pragma unroll
      for (int m = 1; m < 16; m <<= 1) {
        float o0 = __shfl_xor(t3[rf][j][0], m, 64);
        float o1 = __shfl_xor(t3[rf][j][1], m, 64);
        float o2 = __shfl_xor(t3[rf][j][2], m, 64);
        ins3(t3[rf][j][0], t3[rf][j][1], t3[rf][j][2], o0);
        ins3(t3[rf][j][0], t3[rf][j][1], t3[rf][j][2], o1);
        ins3(t3[rf][j][0], t3[rf][j][1], t3[rf][j][2], o2);
      }
  if ((l & 15) == 0) {
    int q = l >> 4;
#pragma unroll
    for (int rf = 0; rf < 4; ++rf)
#pragma unroll
      for (int j = 0; j < 4; ++j) {
        int row = R0 + rf * 16 + q * 4 + j;
        float* p = part + ((size_t)row * 8 + split) * 3;
        p[0] = t3[rf][j][0];
        p[1] = t3[rf][j][1];
        p[2] = t3[rf][j][2];
      }
  }
}

// ---------------------------------------------------------------------------
// merge: per row fold 8 splits x 3 candidates, add |s|^2, sqrt, entropy.
// ---------------------------------------------------------------------------
__global__ void merge_kernel(const float* __restrict__ part, const float* __restrict__ s2,
                             float* __restrict__ eout) {
  int r = blockIdx.x * 256 + threadIdx.x;  // 16384
  const float* p = part + (size_t)r * 24;
  float u0 = 1e30f, u1 = 1e30f, u2 = 1e30f;
#pragma unroll
  for (int i = 0; i < 24; ++i) ins3(u0, u1, u2, p[i]);
  float sv = s2[r];
  float d0 = sqrtf(fmaxf(sv + u0, 0.f));
  float d1 = sqrtf(fmaxf(sv + u1, 0.f));
  float d2 = sqrtf(fmaxf(sv + u2, 0.f));
  eout[r] = (d0 + d1 + d2) * 0.5f;
}

extern "C" void kernel_launch(void* const* d_in, const int* in_sizes, int n_in,
                              void* d_out, int out_size, void* d_ws, size_t ws_size,
                              hipStream_t stream) {
  const float* xsrc = (const float*)d_in[0];
  const float* xtgt = (const float*)d_in[1];
  const float* W1 = (const float*)d_in[2];
  const float* b1 = (const float*)d_in[3];
  const float* W2 = (const float*)d_in[4];
  const float* b2 = (const float*)d_in[5];
  const float* W3 = (const float*)d_in[6];
  const float* b3 = (const float*)d_in[7];
  const float* gm = (const float*)d_in[8];
  const float* bt = (const float*)d_in[9];
  float* out = (float*)d_out;
  unsigned short* ws16 = (unsigned short*)d_ws;
  unsigned char* wsb = (unsigned char*)d_ws;

  prep_weights<<<80, 256, 0, stream>>>(W1, W2, W3, ws16);
  encode_kernel<<<512, 256, 0, stream>>>(xsrc, xtgt, b1, b2, b3, gm, bt, out, ws16);
  if (ws_size >= WS_NEED) {
    repack_fp8<<<1024, 256, 0, stream>>>(ws16, wsb);
    dist8_kernel<<<512, 256, 0, stream>>>(wsb + OFF_SRC8, wsb + OFF_TGT8,
                                          (const float*)(wsb + OFF_T2),
                                          (float*)(wsb + OFF_P));
  } else {
    dist_kernel<<<256, 512, 0, stream>>>(ws16 + OFF_SRCF / 2, ws16 + OFF_TGTF / 2,
                                         (const float*)(wsb + OFF_T2),
                                         (float*)(wsb + OFF_P));
  }
  merge_kernel<<<64, 256, 0, stream>>>((const float*)(wsb + OFF_P),
                                       (const float*)(wsb + OFF_S2),
                                       out + 4194304);
}